// Round 2
// baseline (299.204 us; speedup 1.0000x reference)
//
#include <hip/hip_runtime.h>
#include <hip/hip_bf16.h>
#include <cstdint>

#define BATCH   2048
#define INDIM   256
#define OUTDIM  256
#define KGRID   300   // fourier modes k = 1..300

typedef __attribute__((ext_vector_type(4))) float f32x4;
typedef __attribute__((ext_vector_type(8))) short bf16x8;

__device__ __forceinline__ uint32_t pack_bf16x2(float lo, float hi) {
    union { __hip_bfloat162 h; uint32_t u; } cv;
    cv.h = __float22bfloat162_rn(make_float2(lo, hi));
    return cv.u;
}

// ---------------------------------------------------------------------------
// Kernel 1: fourier path partials, split-K MFMA GEMM, NO atomics.
// Each block writes its own [s][b-tile][j-tile] region of ws exactly once.
//
// Contraction index kk = 2*k + d  (d=0: cos*Fc, d=1: sin*Fs), length 600/i.
// Grid: (8 b-blocks of 256 rows, 2 j-blocks of 128 cols, S i-splits).
// Block: 256 threads = 4 waves (2m x 2n), wave tile 64x64, TWO m-subtiles
// per wave -> 128 f32 acc regs, so each LDS B-tile feeds 256 rows.
// Per (i, chunk of 32 k): A[2][128 rows][64 kk] bf16 generated via
// sincos + Chebyshev recurrence; B[128 j][64 kk] bf16 reg-staged from fp32
// coeffs. LDS rows are 128B, XOR-swizzled in 16B chunks (sub ^ (row&7)) so
// ds_read_b128 fragment reads are conflict-free.
// ---------------------------------------------------------------------------
__global__ __launch_bounds__(256, 2) void fourier_kernel(
    const float* __restrict__ x, const float* __restrict__ fc,
    float* __restrict__ ws, int ips /* i-values per split */)
{
    __shared__ uint4 Abuf[2][128][8];   // 32 KiB: [msub][row][16B-chunk]
    __shared__ uint4 Bbuf[128][8];      // 16 KiB: [j][16B-chunk]

    const int tid  = threadIdx.x;
    const int b0   = blockIdx.x * 256;
    const int j0   = blockIdx.y * 128;
    const int i0   = blockIdx.z * ips;

    const int lane = tid & 63;
    const int wave = tid >> 6;
    const int wm   = wave >> 1, wn = wave & 1;
    const int lrow = lane & 15, lgrp = lane >> 4;

    const int grow = tid >> 1;   // A-gen row 0..127
    const int gh   = tid & 1;    // A-gen half (k 0..15 or 16..31 of chunk)

    f32x4 acc[2][4][4] = {};

    #pragma unroll 1
    for (int il = 0; il < ips; ++il) {
        const int i = i0 + il;
        // per-(b,i) constants for the Chebyshev recurrence (both msubs)
        float th[2], c1[2], s1[2], t2[2];
        th[0] = x[(size_t)(b0 + grow)       * INDIM + i];
        th[1] = x[(size_t)(b0 + 128 + grow) * INDIM + i];
        #pragma unroll
        for (int m = 0; m < 2; ++m) {
            __sincosf(th[m], &s1[m], &c1[m]);
            t2[m] = 2.f * c1[m];
        }

        #pragma unroll 1
        for (int ch = 0; ch < 10; ++ch) {       // 10 chunks of 32 k (last padded)
            // ---------------- phase 1: stage B, generate A ----------------
            #pragma unroll
            for (int r = 0; r < 4; ++r) {       // 1024 16B-chunks / 256 threads
                int flat = r * 256 + tid;
                int jl = flat >> 3, sub = flat & 7;
                int kb = ch * 32 + sub * 4;
                if (kb > KGRID - 4) kb = KGRID - 4;   // clamp; padded kk get A=0
                const float* pc = fc + ((size_t)(j0 + jl) * INDIM + i) * KGRID + kb;
                const float* ps = pc + (size_t)OUTDIM * INDIM * KGRID;
                float4 vc = *reinterpret_cast<const float4*>(pc);
                float4 vs = *reinterpret_cast<const float4*>(ps);
                uint4 wv;
                wv.x = pack_bf16x2(vc.x, vs.x);
                wv.y = pack_bf16x2(vc.y, vs.y);
                wv.z = pack_bf16x2(vc.z, vs.z);
                wv.w = pack_bf16x2(vc.w, vs.w);
                Bbuf[jl][sub ^ (jl & 7)] = wv;
            }
            #pragma unroll
            for (int m = 0; m < 2; ++m) {
                const int k0 = ch * 32 + gh * 16;   // 0-based k of first element
                float ck, sk;
                __sincosf(th[m] * (float)(k0 + 1), &sk, &ck);
                // previous value (k0-1) by backward rotation
                float cp = __builtin_fmaf(ck, c1[m],  sk * s1[m]);
                float sp = __builtin_fmaf(sk, c1[m], -ck * s1[m]);
                const int swz = grow & 7;
                #pragma unroll
                for (int c = 0; c < 4; ++c) {
                    uint32_t uu[4];
                    #pragma unroll
                    for (int qq = 0; qq < 4; ++qq) {
                        const int kidx = k0 + c * 4 + qq;
                        float cc = (kidx < KGRID) ? ck : 0.f;
                        float ss = (kidx < KGRID) ? sk : 0.f;
                        uu[qq] = pack_bf16x2(cc, ss);
                        float cn = __builtin_fmaf(t2[m], ck, -cp);
                        float sn = __builtin_fmaf(t2[m], sk, -sp);
                        cp = ck; sp = sk; ck = cn; sk = sn;
                    }
                    Abuf[m][grow][(gh * 4 + c) ^ swz] =
                        make_uint4(uu[0], uu[1], uu[2], uu[3]);
                }
            }
            __syncthreads();
            // ---------------- phase 2: 64 MFMA ----------------
            #pragma unroll
            for (int s = 0; s < 2; ++s) {       // two K=32 steps
                bf16x8 bfr[4];
                #pragma unroll
                for (int nf = 0; nf < 4; ++nf) {
                    const int jl = wn * 64 + nf * 16 + lrow;
                    uint4 t = Bbuf[jl][(s * 4 + lgrp) ^ (jl & 7)];
                    bfr[nf] = *reinterpret_cast<bf16x8*>(&t);
                }
                #pragma unroll
                for (int m = 0; m < 2; ++m) {
                    #pragma unroll
                    for (int mf = 0; mf < 4; ++mf) {
                        const int rowA = wm * 64 + mf * 16 + lrow;
                        uint4 t = Abuf[m][rowA][(s * 4 + lgrp) ^ (rowA & 7)];
                        bf16x8 af = *reinterpret_cast<bf16x8*>(&t);
                        #pragma unroll
                        for (int nf = 0; nf < 4; ++nf)
                            acc[m][mf][nf] = __builtin_amdgcn_mfma_f32_16x16x32_bf16(
                                af, bfr[nf], acc[m][mf][nf], 0, 0, 0);
                    }
                }
            }
            __syncthreads();
        }
    }

    // epilogue: write per-split partial tile (single writer per element)
    float* pws = ws + (size_t)blockIdx.z * BATCH * OUTDIM;
    #pragma unroll
    for (int m = 0; m < 2; ++m)
        #pragma unroll
        for (int mf = 0; mf < 4; ++mf)
            #pragma unroll
            for (int nf = 0; nf < 4; ++nf)
                #pragma unroll
                for (int r = 0; r < 4; ++r) {
                    int b = b0 + m * 128 + wm * 64 + mf * 16 + lgrp * 4 + r;
                    int j = j0 + wn * 64 + nf * 16 + lrow;
                    pws[(size_t)b * OUTDIM + j] = acc[m][mf][nf][r];
                }
}

// ---------------------------------------------------------------------------
// Kernel 2: out[b,j] = silu(x[b,:] @ W[:,j]) + sum_s ws[s][b][j]
// Single writer of d_out, no RMW, no atomics.
// ---------------------------------------------------------------------------
__global__ __launch_bounds__(256) void combine_kernel(
    const float* __restrict__ x, const float* __restrict__ w,
    const float* __restrict__ ws, float* __restrict__ out, int nsplit)
{
    __shared__ float Xs[64][16];
    __shared__ float Wt[16][68];   // +4 pad: kill bank conflicts

    const int tid = threadIdx.x;
    const int b0 = blockIdx.x * 64;
    const int j0 = blockIdx.y * 64;
    const int tx = tid & 15, ty = tid >> 4;

    float acc[4][4] = {};

    for (int kb = 0; kb < INDIM; kb += 16) {
        {   // stage X tile: 64 rows x 16 k
            int m = tid >> 2, kq = (tid & 3) * 4;
            float4 v = *reinterpret_cast<const float4*>(
                &x[(size_t)(b0 + m) * INDIM + kb + kq]);
            Xs[m][kq+0] = v.x; Xs[m][kq+1] = v.y; Xs[m][kq+2] = v.z; Xs[m][kq+3] = v.w;
        }
        {   // stage W tile: 16 k x 64 j
            int kr = tid >> 4, jc = (tid & 15) * 4;
            float4 v = *reinterpret_cast<const float4*>(
                &w[(size_t)(kb + kr) * OUTDIM + j0 + jc]);
            Wt[kr][jc+0] = v.x; Wt[kr][jc+1] = v.y; Wt[kr][jc+2] = v.z; Wt[kr][jc+3] = v.w;
        }
        __syncthreads();
        #pragma unroll
        for (int kk = 0; kk < 16; ++kk) {
            float a[4], b[4];
            #pragma unroll
            for (int q = 0; q < 4; ++q) { a[q] = Xs[ty*4+q][kk]; b[q] = Wt[kk][tx*4+q]; }
            #pragma unroll
            for (int q = 0; q < 4; ++q)
                #pragma unroll
                for (int p = 0; p < 4; ++p)
                    acc[q][p] = __builtin_fmaf(a[q], b[p], acc[q][p]);
        }
        __syncthreads();
    }

    // sum split partials (coalesced float4 per row)
    float psum[4][4] = {};
    for (int s = 0; s < nsplit; ++s) {
        const float* base = ws + (size_t)s * BATCH * OUTDIM;
        #pragma unroll
        for (int q = 0; q < 4; ++q) {
            float4 pv = *reinterpret_cast<const float4*>(
                &base[(size_t)(b0 + ty*4 + q) * OUTDIM + j0 + tx*4]);
            psum[q][0] += pv.x; psum[q][1] += pv.y;
            psum[q][2] += pv.z; psum[q][3] += pv.w;
        }
    }

    #pragma unroll
    for (int q = 0; q < 4; ++q)
        #pragma unroll
        for (int p = 0; p < 4; ++p) {
            float v = acc[q][p];
            float sv = v / (1.f + __expf(-v));   // SCALE_BASE = 1
            out[(size_t)(b0 + ty*4 + q) * OUTDIM + (j0 + tx*4 + p)] =
                sv + psum[q][p];                 // SCALE_FOURIER = 1
        }
}

// ---------------------------------------------------------------------------
extern "C" void kernel_launch(void* const* d_in, const int* in_sizes, int n_in,
                              void* d_out, int out_size, void* d_ws, size_t ws_size,
                              hipStream_t stream) {
    const float* x  = (const float*)d_in[0];   // [2048, 256]
    const float* bw = (const float*)d_in[1];   // [256, 256]
    const float* fc = (const float*)d_in[2];   // [2, 256, 256, 300]
    float* out = (float*)d_out;                // [2048, 256]
    float* ws  = (float*)d_ws;

    // pick split count that fits the workspace (needs S * 2 MB)
    const size_t per = (size_t)BATCH * OUTDIM * sizeof(float);
    int S = 32;
    while (S > 1 && (size_t)S * per > ws_size) S >>= 1;
    const int ips = INDIM / S;   // i-values per split

    // 1) fourier partials into ws (each element single-writer)
    fourier_kernel<<<dim3(BATCH / 256, OUTDIM / 128, S), 256, 0, stream>>>(
        x, fc, ws, ips);
    // 2) base GEMM + silu + partial reduction -> out (single writer)
    combine_kernel<<<dim3(BATCH / 64, OUTDIM / 64), 256, 0, stream>>>(
        x, bw, ws, out, S);
}

// Round 3
// 244.483 us; speedup vs baseline: 1.2238x; 1.2238x over previous
//
#include <hip/hip_runtime.h>
#include <hip/hip_bf16.h>
#include <cstdint>

#define BATCH   2048
#define INDIM   256
#define OUTDIM  256
#define KGRID   300   // fourier modes k = 1..300
#define NCHUNK  10    // chunks of 32 k (last padded)

typedef __attribute__((ext_vector_type(4))) float f32x4;
typedef __attribute__((ext_vector_type(8))) short bf16x8;

__device__ __forceinline__ uint32_t pack_bf16x2(float lo, float hi) {
    union { __hip_bfloat162 h; uint32_t u; } cv;
    cv.h = __float22bfloat162_rn(make_float2(lo, hi));
    return cv.u;
}

__device__ __forceinline__ void load_lds16(const void* g, void* l) {
    __builtin_amdgcn_global_load_lds(
        (const __attribute__((address_space(1))) void*)g,
        (__attribute__((address_space(3))) void*)l, 16, 0, 0);
}

// packed coeff tensor: [i][ch][j][sub] of uint4 (4 k-values, (cos,sin) bf16 pairs)
// position sub holds k-group (sub ^ (j & 7))  -> pre-applied LDS swizzle.
#define PACKED_U4 ((size_t)INDIM * NCHUNK * OUTDIM * 8)       // 5,242,880
#define PACKED_BYTES (PACKED_U4 * 16)                         // 83.9 MB

// ---------------------------------------------------------------------------
// Kernel 0: pack fc (fp32 [2][j][i][k]) -> bf16 pre-swizzled [i][ch][j][sub]
// ---------------------------------------------------------------------------
__global__ __launch_bounds__(256) void pack_kernel(
    const float* __restrict__ fc, uint4* __restrict__ pk)
{
    size_t tidg = (size_t)blockIdx.x * 256 + threadIdx.x;   // one uint4 each
    int sub = tidg & 7;
    int j   = (tidg >> 3) & 255;
    int ich = (int)(tidg >> 11);        // i*10 + ch, 0..2559
    int ch  = ich % NCHUNK;
    int i   = ich / NCHUNK;
    int kb  = ch * 32 + (sub ^ (j & 7)) * 4;
    if (kb > KGRID - 4) kb = KGRID - 4;   // clamp; A=0 kills padded kk
    const float* pc = fc + ((size_t)j * INDIM + i) * KGRID + kb;
    const float* ps = pc + (size_t)OUTDIM * INDIM * KGRID;
    float4 vc = *reinterpret_cast<const float4*>(pc);
    float4 vs = *reinterpret_cast<const float4*>(ps);
    uint4 wv;
    wv.x = pack_bf16x2(vc.x, vs.x);
    wv.y = pack_bf16x2(vc.y, vs.y);
    wv.z = pack_bf16x2(vc.z, vs.z);
    wv.w = pack_bf16x2(vc.w, vs.w);
    pk[tidg] = wv;
}

// ---------------------------------------------------------------------------
// Kernel 1 (main path): fourier partials via MFMA; B staged by global_load_lds
// DMA (double-buffered, issued one iteration ahead); A generated in-register
// (sincos + Chebyshev) into swizzled LDS. XCD-chunked block swizzle.
// Grid 8 x 2 x 32 = 512 blocks, 256 threads = 4 waves, wave tile 64x64 x 2 msub.
// ---------------------------------------------------------------------------
__global__ __launch_bounds__(256, 2) void fourier_dma_kernel(
    const float* __restrict__ x, const uint4* __restrict__ pk,
    float* __restrict__ part)
{
    __shared__ uint4 Abuf[2][128][8];   // 32 KiB [msub][row][chunk]
    __shared__ uint4 Bbuf[2][128][8];   // 32 KiB double-buffered DMA dest

    const int tid = threadIdx.x;
    // XCD-chunked bijective remap: hw flat -> logical L, chunk of 64 per XCD
    const int flat = blockIdx.x + (blockIdx.y << 3) + (blockIdx.z << 4);
    const int L  = (flat & 7) * 64 + (flat >> 3);
    const int b0 = (L & 7) * 256;
    const int j0 = ((L >> 3) & 1) * 128;
    const int z  = L >> 4;              // i-split 0..31
    const int i0 = z * 8;

    const int lane = tid & 63, wave = tid >> 6;
    const int wm = wave >> 1, wn = wave & 1;
    const int lrow = lane & 15, lgrp = lane >> 4;
    const int grow = tid >> 1,  gh = tid & 1;
    const int q4 = wave * 4;            // this wave's 4 DMA issues

    f32x4 acc[2][4][4] = {};
    float thc[2], thn[2], c1[2], s1[2], t2[2];

    thn[0] = x[(size_t)(b0 + grow) * INDIM + i0];
    thn[1] = x[(size_t)(b0 + 128 + grow) * INDIM + i0];

    // prologue: DMA B(il=0, ch=0) into Bbuf[0]
    {
        const uint4* src = pk + ((size_t)(i0 * NCHUNK) * 256 + j0) * 8;
        #pragma unroll
        for (int q = 0; q < 4; ++q)
            load_lds16(src + (q4 + q) * 64 + lane,
                       (char*)&Bbuf[0][0][0] + (q4 + q) * 1024);
    }

    int il = 0, ch = 0;
    #pragma unroll 1
    for (int t = 0; t < 8 * NCHUNK; ++t) {
        if (ch == 0) {
            thc[0] = thn[0]; thc[1] = thn[1];
            #pragma unroll
            for (int m = 0; m < 2; ++m) {
                __sincosf(thc[m], &s1[m], &c1[m]);
                t2[m] = 2.f * c1[m];
            }
            int iln = (il + 1 < 8) ? il + 1 : il;   // prefetch x for next il
            thn[0] = x[(size_t)(b0 + grow) * INDIM + i0 + iln];
            thn[1] = x[(size_t)(b0 + 128 + grow) * INDIM + i0 + iln];
        }
        // issue DMA for t+1 into the other Bbuf (in flight across barrier's drain
        // window is covered by A-gen below)
        {
            int il2 = il, ch2 = ch + 1;
            if (ch2 == NCHUNK) { ch2 = 0; il2 = (il + 1 < 8) ? il + 1 : il; }
            const uint4* src =
                pk + ((size_t)((i0 + il2) * NCHUNK + ch2) * 256 + j0) * 8;
            char* dst = (char*)&Bbuf[(t + 1) & 1][0][0];
            #pragma unroll
            for (int q = 0; q < 4; ++q)
                load_lds16(src + (q4 + q) * 64 + lane, dst + (q4 + q) * 1024);
        }
        // ---- A-gen: cos/sin via Chebyshev recurrence -> swizzled Abuf ----
        #pragma unroll
        for (int m = 0; m < 2; ++m) {
            const int k0 = ch * 32 + gh * 16;
            float ck, sk;
            __sincosf(thc[m] * (float)(k0 + 1), &sk, &ck);
            float cp = __builtin_fmaf(ck, c1[m],  sk * s1[m]);
            float sp = __builtin_fmaf(sk, c1[m], -ck * s1[m]);
            const int swz = grow & 7;
            #pragma unroll
            for (int c = 0; c < 4; ++c) {
                uint32_t uu[4];
                #pragma unroll
                for (int qq = 0; qq < 4; ++qq) {
                    uu[qq] = pack_bf16x2(ck, sk);
                    float cn = __builtin_fmaf(t2[m], ck, -cp);
                    float sn = __builtin_fmaf(t2[m], sk, -sp);
                    cp = ck; sp = sk; ck = cn; sk = sn;
                }
                if (ch == NCHUNK - 1) {          // zero padded k >= 300
                    #pragma unroll
                    for (int qq = 0; qq < 4; ++qq)
                        if (k0 + c * 4 + qq >= KGRID) uu[qq] = 0u;
                }
                Abuf[m][grow][(gh * 4 + c) ^ swz] =
                    make_uint4(uu[0], uu[1], uu[2], uu[3]);
            }
        }
        __syncthreads();    // drains A ds_writes + this tile's DMA
        // ---- 64 MFMA ----
        __builtin_amdgcn_s_setprio(1);
        #pragma unroll
        for (int s = 0; s < 2; ++s) {
            bf16x8 bfr[4];
            #pragma unroll
            for (int nf = 0; nf < 4; ++nf) {
                const int jl = wn * 64 + nf * 16 + lrow;
                uint4 tv = Bbuf[t & 1][jl][(s * 4 + lgrp) ^ (jl & 7)];
                bfr[nf] = *reinterpret_cast<bf16x8*>(&tv);
            }
            #pragma unroll
            for (int m = 0; m < 2; ++m) {
                #pragma unroll
                for (int mf = 0; mf < 4; ++mf) {
                    const int rowA = wm * 64 + mf * 16 + lrow;
                    uint4 tv = Abuf[m][rowA][(s * 4 + lgrp) ^ (rowA & 7)];
                    bf16x8 af = *reinterpret_cast<bf16x8*>(&tv);
                    #pragma unroll
                    for (int nf = 0; nf < 4; ++nf)
                        acc[m][mf][nf] = __builtin_amdgcn_mfma_f32_16x16x32_bf16(
                            af, bfr[nf], acc[m][mf][nf], 0, 0, 0);
                }
            }
        }
        __builtin_amdgcn_s_setprio(0);
        __syncthreads();
        if (++ch == NCHUNK) { ch = 0; ++il; }
    }

    // epilogue: per-split partial tile (single writer per element)
    float* pws = part + (size_t)z * BATCH * OUTDIM;
    #pragma unroll
    for (int m = 0; m < 2; ++m)
        #pragma unroll
        for (int mf = 0; mf < 4; ++mf)
            #pragma unroll
            for (int nf = 0; nf < 4; ++nf)
                #pragma unroll
                for (int r = 0; r < 4; ++r) {
                    int b = b0 + m * 128 + wm * 64 + mf * 16 + lgrp * 4 + r;
                    int j = j0 + wn * 64 + nf * 16 + lrow;
                    pws[(size_t)b * OUTDIM + j] = acc[m][mf][nf][r];
                }
}

// ---------------------------------------------------------------------------
// Fallback fourier kernel (round-2, reg-staged): used when ws is too small.
// ---------------------------------------------------------------------------
__global__ __launch_bounds__(256, 2) void fourier_kernel_fb(
    const float* __restrict__ x, const float* __restrict__ fc,
    float* __restrict__ ws, int ips)
{
    __shared__ uint4 Abuf[2][128][8];
    __shared__ uint4 Bbuf[128][8];

    const int tid  = threadIdx.x;
    const int b0   = blockIdx.x * 256;
    const int j0   = blockIdx.y * 128;
    const int i0   = blockIdx.z * ips;

    const int lane = tid & 63, wave = tid >> 6;
    const int wm   = wave >> 1, wn = wave & 1;
    const int lrow = lane & 15, lgrp = lane >> 4;
    const int grow = tid >> 1,  gh = tid & 1;

    f32x4 acc[2][4][4] = {};

    #pragma unroll 1
    for (int il = 0; il < ips; ++il) {
        const int i = i0 + il;
        float th[2], c1[2], s1[2], t2[2];
        th[0] = x[(size_t)(b0 + grow)       * INDIM + i];
        th[1] = x[(size_t)(b0 + 128 + grow) * INDIM + i];
        #pragma unroll
        for (int m = 0; m < 2; ++m) {
            __sincosf(th[m], &s1[m], &c1[m]);
            t2[m] = 2.f * c1[m];
        }
        #pragma unroll 1
        for (int ch = 0; ch < NCHUNK; ++ch) {
            #pragma unroll
            for (int r = 0; r < 4; ++r) {
                int flat = r * 256 + tid;
                int jl = flat >> 3, sub = flat & 7;
                int kb = ch * 32 + sub * 4;
                if (kb > KGRID - 4) kb = KGRID - 4;
                const float* pc = fc + ((size_t)(j0 + jl) * INDIM + i) * KGRID + kb;
                const float* ps = pc + (size_t)OUTDIM * INDIM * KGRID;
                float4 vc = *reinterpret_cast<const float4*>(pc);
                float4 vs = *reinterpret_cast<const float4*>(ps);
                uint4 wv;
                wv.x = pack_bf16x2(vc.x, vs.x);
                wv.y = pack_bf16x2(vc.y, vs.y);
                wv.z = pack_bf16x2(vc.z, vs.z);
                wv.w = pack_bf16x2(vc.w, vs.w);
                Bbuf[jl][sub ^ (jl & 7)] = wv;
            }
            #pragma unroll
            for (int m = 0; m < 2; ++m) {
                const int k0 = ch * 32 + gh * 16;
                float ck, sk;
                __sincosf(th[m] * (float)(k0 + 1), &sk, &ck);
                float cp = __builtin_fmaf(ck, c1[m],  sk * s1[m]);
                float sp = __builtin_fmaf(sk, c1[m], -ck * s1[m]);
                const int swz = grow & 7;
                #pragma unroll
                for (int c = 0; c < 4; ++c) {
                    uint32_t uu[4];
                    #pragma unroll
                    for (int qq = 0; qq < 4; ++qq) {
                        const int kidx = k0 + c * 4 + qq;
                        float cc = (kidx < KGRID) ? ck : 0.f;
                        float ss = (kidx < KGRID) ? sk : 0.f;
                        uu[qq] = pack_bf16x2(cc, ss);
                        float cn = __builtin_fmaf(t2[m], ck, -cp);
                        float sn = __builtin_fmaf(t2[m], sk, -sp);
                        cp = ck; sp = sk; ck = cn; sk = sn;
                    }
                    Abuf[m][grow][(gh * 4 + c) ^ swz] =
                        make_uint4(uu[0], uu[1], uu[2], uu[3]);
                }
            }
            __syncthreads();
            #pragma unroll
            for (int s = 0; s < 2; ++s) {
                bf16x8 bfr[4];
                #pragma unroll
                for (int nf = 0; nf < 4; ++nf) {
                    const int jl = wn * 64 + nf * 16 + lrow;
                    uint4 tv = Bbuf[jl][(s * 4 + lgrp) ^ (jl & 7)];
                    bfr[nf] = *reinterpret_cast<bf16x8*>(&tv);
                }
                #pragma unroll
                for (int m = 0; m < 2; ++m) {
                    #pragma unroll
                    for (int mf = 0; mf < 4; ++mf) {
                        const int rowA = wm * 64 + mf * 16 + lrow;
                        uint4 tv = Abuf[m][rowA][(s * 4 + lgrp) ^ (rowA & 7)];
                        bf16x8 af = *reinterpret_cast<bf16x8*>(&tv);
                        #pragma unroll
                        for (int nf = 0; nf < 4; ++nf)
                            acc[m][mf][nf] = __builtin_amdgcn_mfma_f32_16x16x32_bf16(
                                af, bfr[nf], acc[m][mf][nf], 0, 0, 0);
                    }
                }
            }
            __syncthreads();
        }
    }

    float* pws = ws + (size_t)blockIdx.z * BATCH * OUTDIM;
    #pragma unroll
    for (int m = 0; m < 2; ++m)
        #pragma unroll
        for (int mf = 0; mf < 4; ++mf)
            #pragma unroll
            for (int nf = 0; nf < 4; ++nf)
                #pragma unroll
                for (int r = 0; r < 4; ++r) {
                    int b = b0 + m * 128 + wm * 64 + mf * 16 + lgrp * 4 + r;
                    int j = j0 + wn * 64 + nf * 16 + lrow;
                    pws[(size_t)b * OUTDIM + j] = acc[m][mf][nf][r];
                }
}

// ---------------------------------------------------------------------------
// Kernel 2: out[b,j] = silu(x[b,:] @ W[:,j]) + sum_s part[s][b][j]
// ---------------------------------------------------------------------------
__global__ __launch_bounds__(256) void combine_kernel(
    const float* __restrict__ x, const float* __restrict__ w,
    const float* __restrict__ part, float* __restrict__ out, int nsplit)
{
    __shared__ float Xs[64][16];
    __shared__ float Wt[16][68];

    const int tid = threadIdx.x;
    const int b0 = blockIdx.x * 64;
    const int j0 = blockIdx.y * 64;
    const int tx = tid & 15, ty = tid >> 4;

    float acc[4][4] = {};

    for (int kb = 0; kb < INDIM; kb += 16) {
        {
            int m = tid >> 2, kq = (tid & 3) * 4;
            float4 v = *reinterpret_cast<const float4*>(
                &x[(size_t)(b0 + m) * INDIM + kb + kq]);
            Xs[m][kq+0] = v.x; Xs[m][kq+1] = v.y; Xs[m][kq+2] = v.z; Xs[m][kq+3] = v.w;
        }
        {
            int kr = tid >> 4, jc = (tid & 15) * 4;
            float4 v = *reinterpret_cast<const float4*>(
                &w[(size_t)(kb + kr) * OUTDIM + j0 + jc]);
            Wt[kr][jc+0] = v.x; Wt[kr][jc+1] = v.y; Wt[kr][jc+2] = v.z; Wt[kr][jc+3] = v.w;
        }
        __syncthreads();
        #pragma unroll
        for (int kk = 0; kk < 16; ++kk) {
            float a[4], b[4];
            #pragma unroll
            for (int q = 0; q < 4; ++q) { a[q] = Xs[ty*4+q][kk]; b[q] = Wt[kk][tx*4+q]; }
            #pragma unroll
            for (int q = 0; q < 4; ++q)
                #pragma unroll
                for (int p = 0; p < 4; ++p)
                    acc[q][p] = __builtin_fmaf(a[q], b[p], acc[q][p]);
        }
        __syncthreads();
    }

    float psum[4][4] = {};
    for (int s = 0; s < nsplit; ++s) {
        const float* base = part + (size_t)s * BATCH * OUTDIM;
        #pragma unroll
        for (int q = 0; q < 4; ++q) {
            float4 pv = *reinterpret_cast<const float4*>(
                &base[(size_t)(b0 + ty*4 + q) * OUTDIM + j0 + tx*4]);
            psum[q][0] += pv.x; psum[q][1] += pv.y;
            psum[q][2] += pv.z; psum[q][3] += pv.w;
        }
    }

    #pragma unroll
    for (int q = 0; q < 4; ++q)
        #pragma unroll
        for (int p = 0; p < 4; ++p) {
            float v = acc[q][p];
            float sv = v / (1.f + __expf(-v));
            out[(size_t)(b0 + ty*4 + q) * OUTDIM + (j0 + tx*4 + p)] =
                sv + psum[q][p];
        }
}

// ---------------------------------------------------------------------------
extern "C" void kernel_launch(void* const* d_in, const int* in_sizes, int n_in,
                              void* d_out, int out_size, void* d_ws, size_t ws_size,
                              hipStream_t stream) {
    const float* x  = (const float*)d_in[0];   // [2048, 256]
    const float* bw = (const float*)d_in[1];   // [256, 256]
    const float* fc = (const float*)d_in[2];   // [2, 256, 256, 300]
    float* out = (float*)d_out;                // [2048, 256]

    const size_t per = (size_t)BATCH * OUTDIM * sizeof(float);   // 2 MB/split

    if (ws_size >= PACKED_BYTES + 32 * per) {
        // main path: pack -> DMA fourier -> combine
        uint4* pk   = (uint4*)d_ws;
        float* part = (float*)((char*)d_ws + PACKED_BYTES);
        pack_kernel<<<(int)(PACKED_U4 / 256), 256, 0, stream>>>(fc, pk);
        fourier_dma_kernel<<<dim3(8, 2, 32), 256, 0, stream>>>(x, pk, part);
        combine_kernel<<<dim3(BATCH / 64, OUTDIM / 64), 256, 0, stream>>>(
            x, bw, part, out, 32);
    } else {
        // fallback: round-2 path, auto-shrunk split count
        float* part = (float*)d_ws;
        int S = 32;
        while (S > 1 && (size_t)S * per > ws_size) S >>= 1;
        const int ips = INDIM / S;
        fourier_kernel_fb<<<dim3(BATCH / 256, OUTDIM / 128, S), 256, 0, stream>>>(
            x, fc, part, ips);
        combine_kernel<<<dim3(BATCH / 64, OUTDIM / 64), 256, 0, stream>>>(
            x, bw, part, out, S);
    }
}

// Round 4
// 226.321 us; speedup vs baseline: 1.3220x; 1.0802x over previous
//
#include <hip/hip_runtime.h>
#include <hip/hip_bf16.h>
#include <cstdint>

#define BATCH   2048
#define INDIM   256
#define OUTDIM  256
#define KGRID   300   // fourier modes k = 1..300
#define NCHUNK  10    // chunks of 32 k (last padded)

typedef __attribute__((ext_vector_type(4))) float f32x4;
typedef __attribute__((ext_vector_type(2))) float f32x2;
typedef __attribute__((ext_vector_type(8))) short bf16x8;

__device__ __forceinline__ uint32_t pack_bf16x2(float lo, float hi) {
    union { __hip_bfloat162 h; uint32_t u; } cv;
    cv.h = __float22bfloat162_rn(make_float2(lo, hi));
    return cv.u;
}

// packed fp32x2 FMA with negated addend: d = a*b - c   (one VOP3P instr)
__device__ __forceinline__ f32x2 pk_fma_sub(f32x2 a, f32x2 b, f32x2 c) {
    f32x2 d;
    asm("v_pk_fma_f32 %0, %1, %2, %3 neg_lo:[0,0,1] neg_hi:[0,0,1]"
        : "=v"(d) : "v"(a), "v"(b), "v"(c));
    return d;
}

__device__ __forceinline__ void load_lds16(const void* g, void* l) {
    __builtin_amdgcn_global_load_lds(
        (const __attribute__((address_space(1))) void*)g,
        (__attribute__((address_space(3))) void*)l, 16, 0, 0);
}

// packed coeff tensor: [i][ch][j][sub] of uint4 (4 k-values, (cos,sin) bf16
// pairs); position sub holds k-group (sub ^ (j & 7)) -> pre-applied swizzle.
#define PACKED_U4 ((size_t)INDIM * NCHUNK * OUTDIM * 8)       // 5,242,880
#define PACKED_BYTES (PACKED_U4 * 16)                         // 83.9 MB

// ---------------------------------------------------------------------------
// Kernel 0: pack fc (fp32 [2][j][i][k]) -> bf16 pre-swizzled [i][ch][j][sub]
// ---------------------------------------------------------------------------
__global__ __launch_bounds__(256) void pack_kernel(
    const float* __restrict__ fc, uint4* __restrict__ pk)
{
    size_t tidg = (size_t)blockIdx.x * 256 + threadIdx.x;   // one uint4 each
    int sub = tidg & 7;
    int j   = (tidg >> 3) & 255;
    int ich = (int)(tidg >> 11);        // i*10 + ch, 0..2559
    int ch  = ich % NCHUNK;
    int i   = ich / NCHUNK;
    int kb  = ch * 32 + (sub ^ (j & 7)) * 4;
    if (kb > KGRID - 4) kb = KGRID - 4;   // clamp; A=0 kills padded kk
    const float* pc = fc + ((size_t)j * INDIM + i) * KGRID + kb;
    const float* ps = pc + (size_t)OUTDIM * INDIM * KGRID;
    float4 vc = *reinterpret_cast<const float4*>(pc);
    float4 vs = *reinterpret_cast<const float4*>(ps);
    uint4 wv;
    wv.x = pack_bf16x2(vc.x, vs.x);
    wv.y = pack_bf16x2(vc.y, vs.y);
    wv.z = pack_bf16x2(vc.z, vs.z);
    wv.w = pack_bf16x2(vc.w, vs.w);
    pk[tidg] = wv;
}

// ---------------------------------------------------------------------------
// Kernel 1 (main): fourier partials via MFMA. Block = 128 b-rows x 256 j
// (A-gen done ONCE per (b,i,k) across the grid). B staged by global_load_lds
// DMA (double-buffered, issued one iter ahead); A generated in-register
// (sincos seed + packed-f32 Chebyshev recurrence) into swizzled LDS.
// Grid 16 x 1 x 32 = 512 blocks, 256 threads = 4 waves (2m x 2n),
// wave tile 64 rows x 128 j (2 n-subtiles).
// ---------------------------------------------------------------------------
__global__ __launch_bounds__(256, 2) void fourier_dma_kernel(
    const float* __restrict__ x, const uint4* __restrict__ pk,
    float* __restrict__ part)
{
    __shared__ uint4 Abuf[128][8];      // 16 KiB [row][16B-chunk]
    __shared__ uint4 Bbuf[2][256][8];   // 64 KiB double-buffered DMA dest

    const int tid = threadIdx.x;
    // XCD-chunked bijective remap (512 = 8 XCD x 64): chunk of 64 per XCD;
    // within a chunk, 16 consecutive blocks share one i-split's B stream.
    const int flat = blockIdx.x + (blockIdx.z << 4);
    const int L  = (flat & 7) * 64 + (flat >> 3);
    const int b0 = (L & 15) * 128;
    const int z  = L >> 4;              // i-split 0..31
    const int i0 = z * 8;

    const int lane = tid & 63, wave = tid >> 6;
    const int wm = wave >> 1, wn = wave & 1;
    const int lrow = lane & 15, lgrp = lane >> 4;
    const int grow = tid >> 1,  gh = tid & 1;
    const int q8 = wave * 8;            // this wave's 8 DMA issues

    f32x4 acc[2][4][4] = {};            // [nsub][mf][nf]
    float thc, thn, c1v, s1v, t2v;

    thn = x[(size_t)(b0 + grow) * INDIM + i0];

    // prologue: DMA B(il=0, ch=0) into Bbuf[0]
    {
        const uint4* src = pk + (size_t)(i0 * NCHUNK) * 2048;
        char* dst = (char*)&Bbuf[0][0][0];
        #pragma unroll
        for (int q = 0; q < 8; ++q)
            load_lds16(src + (q8 + q) * 64 + lane, dst + (q8 + q) * 1024);
    }

    int il = 0, ch = 0;
    #pragma unroll 1
    for (int t = 0; t < 8 * NCHUNK; ++t) {
        if (ch == 0) {
            thc = thn;
            __sincosf(thc, &s1v, &c1v);
            t2v = 2.f * c1v;
            int iln = (il + 1 < 8) ? il + 1 : il;   // prefetch x for next il
            thn = x[(size_t)(b0 + grow) * INDIM + i0 + iln];
        }
        // issue DMA for t+1 into the other Bbuf
        {
            int il2 = il, ch2 = ch + 1;
            if (ch2 == NCHUNK) { ch2 = 0; il2 = (il + 1 < 8) ? il + 1 : il; }
            const uint4* src = pk + (size_t)((i0 + il2) * NCHUNK + ch2) * 2048;
            char* dst = (char*)&Bbuf[(t + 1) & 1][0][0];
            #pragma unroll
            for (int q = 0; q < 8; ++q)
                load_lds16(src + (q8 + q) * 64 + lane, dst + (q8 + q) * 1024);
        }
        // ---- A-gen: packed Chebyshev recurrence -> swizzled Abuf ----
        {
            const int k0 = ch * 32 + gh * 16;
            float ck, sk;
            __sincosf(thc * (float)(k0 + 1), &sk, &ck);
            // previous value (k0-1) by backward rotation
            float cp = __builtin_fmaf(ck, c1v,  sk * s1v);
            float sp = __builtin_fmaf(sk, c1v, -ck * s1v);
            f32x2 C; C.x = ck; C.y = sk;
            f32x2 P; P.x = cp; P.y = sp;
            f32x2 T2; T2.x = t2v; T2.y = t2v;
            const int swz = grow & 7;
            #pragma unroll
            for (int c = 0; c < 4; ++c) {
                uint32_t uu[4];
                #pragma unroll
                for (int qq = 0; qq < 4; ++qq) {
                    uu[qq] = pack_bf16x2(C.x, C.y);
                    f32x2 N = pk_fma_sub(T2, C, P);
                    P = C; C = N;
                }
                if (ch == NCHUNK - 1) {          // zero padded k >= 300
                    #pragma unroll
                    for (int qq = 0; qq < 4; ++qq)
                        if (k0 + c * 4 + qq >= KGRID) uu[qq] = 0u;
                }
                Abuf[grow][(gh * 4 + c) ^ swz] =
                    make_uint4(uu[0], uu[1], uu[2], uu[3]);
            }
        }
        __syncthreads();    // drains A ds_writes + this tile's DMA
        // ---- 64 MFMA ----
        __builtin_amdgcn_s_setprio(1);
        #pragma unroll
        for (int s = 0; s < 2; ++s) {
            bf16x8 afr[4];
            #pragma unroll
            for (int mf = 0; mf < 4; ++mf) {
                const int rowA = wm * 64 + mf * 16 + lrow;
                uint4 tv = Abuf[rowA][(s * 4 + lgrp) ^ (rowA & 7)];
                afr[mf] = *reinterpret_cast<bf16x8*>(&tv);
            }
            #pragma unroll
            for (int ns = 0; ns < 2; ++ns)
                #pragma unroll
                for (int nf = 0; nf < 4; ++nf) {
                    const int jl = wn * 128 + ns * 64 + nf * 16 + lrow;
                    uint4 tv = Bbuf[t & 1][jl][(s * 4 + lgrp) ^ (jl & 7)];
                    bf16x8 bfr = *reinterpret_cast<bf16x8*>(&tv);
                    #pragma unroll
                    for (int mf = 0; mf < 4; ++mf)
                        acc[ns][mf][nf] = __builtin_amdgcn_mfma_f32_16x16x32_bf16(
                            afr[mf], bfr, acc[ns][mf][nf], 0, 0, 0);
                }
        }
        __builtin_amdgcn_s_setprio(0);
        __syncthreads();
        if (++ch == NCHUNK) { ch = 0; ++il; }
    }

    // epilogue: per-split partial tile (single writer per element)
    float* pws = part + (size_t)z * BATCH * OUTDIM;
    #pragma unroll
    for (int ns = 0; ns < 2; ++ns)
        #pragma unroll
        for (int mf = 0; mf < 4; ++mf)
            #pragma unroll
            for (int nf = 0; nf < 4; ++nf)
                #pragma unroll
                for (int r = 0; r < 4; ++r) {
                    int b = b0 + wm * 64 + mf * 16 + lgrp * 4 + r;
                    int j = wn * 128 + ns * 64 + nf * 16 + lrow;
                    pws[(size_t)b * OUTDIM + j] = acc[ns][mf][nf][r];
                }
}

// ---------------------------------------------------------------------------
// Fallback fourier kernel (round-2, reg-staged): used when ws is too small.
// ---------------------------------------------------------------------------
__global__ __launch_bounds__(256, 2) void fourier_kernel_fb(
    const float* __restrict__ x, const float* __restrict__ fc,
    float* __restrict__ ws, int ips)
{
    __shared__ uint4 Abuf[2][128][8];
    __shared__ uint4 Bbuf[128][8];

    const int tid  = threadIdx.x;
    const int b0   = blockIdx.x * 256;
    const int j0   = blockIdx.y * 128;
    const int i0   = blockIdx.z * ips;

    const int lane = tid & 63, wave = tid >> 6;
    const int wm   = wave >> 1, wn = wave & 1;
    const int lrow = lane & 15, lgrp = lane >> 4;
    const int grow = tid >> 1,  gh = tid & 1;

    f32x4 acc[2][4][4] = {};

    #pragma unroll 1
    for (int il = 0; il < ips; ++il) {
        const int i = i0 + il;
        float th[2], c1[2], s1[2], t2[2];
        th[0] = x[(size_t)(b0 + grow)       * INDIM + i];
        th[1] = x[(size_t)(b0 + 128 + grow) * INDIM + i];
        #pragma unroll
        for (int m = 0; m < 2; ++m) {
            __sincosf(th[m], &s1[m], &c1[m]);
            t2[m] = 2.f * c1[m];
        }
        #pragma unroll 1
        for (int ch = 0; ch < NCHUNK; ++ch) {
            #pragma unroll
            for (int r = 0; r < 4; ++r) {
                int flat = r * 256 + tid;
                int jl = flat >> 3, sub = flat & 7;
                int kb = ch * 32 + sub * 4;
                if (kb > KGRID - 4) kb = KGRID - 4;
                const float* pc = fc + ((size_t)(j0 + jl) * INDIM + i) * KGRID + kb;
                const float* ps = pc + (size_t)OUTDIM * INDIM * KGRID;
                float4 vc = *reinterpret_cast<const float4*>(pc);
                float4 vs = *reinterpret_cast<const float4*>(ps);
                uint4 wv;
                wv.x = pack_bf16x2(vc.x, vs.x);
                wv.y = pack_bf16x2(vc.y, vs.y);
                wv.z = pack_bf16x2(vc.z, vs.z);
                wv.w = pack_bf16x2(vc.w, vs.w);
                Bbuf[jl][sub ^ (jl & 7)] = wv;
            }
            #pragma unroll
            for (int m = 0; m < 2; ++m) {
                const int k0 = ch * 32 + gh * 16;
                float ck, sk;
                __sincosf(th[m] * (float)(k0 + 1), &sk, &ck);
                float cp = __builtin_fmaf(ck, c1[m],  sk * s1[m]);
                float sp = __builtin_fmaf(sk, c1[m], -ck * s1[m]);
                const int swz = grow & 7;
                #pragma unroll
                for (int c = 0; c < 4; ++c) {
                    uint32_t uu[4];
                    #pragma unroll
                    for (int qq = 0; qq < 4; ++qq) {
                        const int kidx = k0 + c * 4 + qq;
                        float cc = (kidx < KGRID) ? ck : 0.f;
                        float ss = (kidx < KGRID) ? sk : 0.f;
                        uu[qq] = pack_bf16x2(cc, ss);
                        float cn = __builtin_fmaf(t2[m], ck, -cp);
                        float sn = __builtin_fmaf(t2[m], sk, -sp);
                        cp = ck; sp = sk; ck = cn; sk = sn;
                    }
                    Abuf[m][grow][(gh * 4 + c) ^ swz] =
                        make_uint4(uu[0], uu[1], uu[2], uu[3]);
                }
            }
            __syncthreads();
            #pragma unroll
            for (int s = 0; s < 2; ++s) {
                bf16x8 bfr[4];
                #pragma unroll
                for (int nf = 0; nf < 4; ++nf) {
                    const int jl = wn * 64 + nf * 16 + lrow;
                    uint4 tv = Bbuf[jl][(s * 4 + lgrp) ^ (jl & 7)];
                    bfr[nf] = *reinterpret_cast<bf16x8*>(&tv);
                }
                #pragma unroll
                for (int m = 0; m < 2; ++m) {
                    #pragma unroll
                    for (int mf = 0; mf < 4; ++mf) {
                        const int rowA = wm * 64 + mf * 16 + lrow;
                        uint4 tv = Abuf[m][rowA][(s * 4 + lgrp) ^ (rowA & 7)];
                        bf16x8 af = *reinterpret_cast<bf16x8*>(&tv);
                        #pragma unroll
                        for (int nf = 0; nf < 4; ++nf)
                            acc[m][mf][nf] = __builtin_amdgcn_mfma_f32_16x16x32_bf16(
                                af, bfr[nf], acc[m][mf][nf], 0, 0, 0);
                    }
                }
            }
            __syncthreads();
        }
    }

    float* pws = ws + (size_t)blockIdx.z * BATCH * OUTDIM;
    #pragma unroll
    for (int m = 0; m < 2; ++m)
        #pragma unroll
        for (int mf = 0; mf < 4; ++mf)
            #pragma unroll
            for (int nf = 0; nf < 4; ++nf)
                #pragma unroll
                for (int r = 0; r < 4; ++r) {
                    int b = b0 + m * 128 + wm * 64 + mf * 16 + lgrp * 4 + r;
                    int j = j0 + wn * 64 + nf * 16 + lrow;
                    pws[(size_t)b * OUTDIM + j] = acc[m][mf][nf][r];
                }
}

// ---------------------------------------------------------------------------
// Kernel 2: out[b,j] = silu(x[b,:] @ W[:,j]) + sum_s part[s][b][j]
// ---------------------------------------------------------------------------
__global__ __launch_bounds__(256) void combine_kernel(
    const float* __restrict__ x, const float* __restrict__ w,
    const float* __restrict__ part, float* __restrict__ out, int nsplit)
{
    __shared__ float Xs[64][16];
    __shared__ float Wt[16][68];

    const int tid = threadIdx.x;
    const int b0 = blockIdx.x * 64;
    const int j0 = blockIdx.y * 64;
    const int tx = tid & 15, ty = tid >> 4;

    float acc[4][4] = {};

    for (int kb = 0; kb < INDIM; kb += 16) {
        {
            int m = tid >> 2, kq = (tid & 3) * 4;
            float4 v = *reinterpret_cast<const float4*>(
                &x[(size_t)(b0 + m) * INDIM + kb + kq]);
            Xs[m][kq+0] = v.x; Xs[m][kq+1] = v.y; Xs[m][kq+2] = v.z; Xs[m][kq+3] = v.w;
        }
        {
            int kr = tid >> 4, jc = (tid & 15) * 4;
            float4 v = *reinterpret_cast<const float4*>(
                &w[(size_t)(kb + kr) * OUTDIM + j0 + jc]);
            Wt[kr][jc+0] = v.x; Wt[kr][jc+1] = v.y; Wt[kr][jc+2] = v.z; Wt[kr][jc+3] = v.w;
        }
        __syncthreads();
        #pragma unroll
        for (int kk = 0; kk < 16; ++kk) {
            float a[4], b[4];
            #pragma unroll
            for (int q = 0; q < 4; ++q) { a[q] = Xs[ty*4+q][kk]; b[q] = Wt[kk][tx*4+q]; }
            #pragma unroll
            for (int q = 0; q < 4; ++q)
                #pragma unroll
                for (int p = 0; p < 4; ++p)
                    acc[q][p] = __builtin_fmaf(a[q], b[p], acc[q][p]);
        }
        __syncthreads();
    }

    float psum[4][4] = {};
    for (int s = 0; s < nsplit; ++s) {
        const float* base = part + (size_t)s * BATCH * OUTDIM;
        #pragma unroll
        for (int q = 0; q < 4; ++q) {
            float4 pv = *reinterpret_cast<const float4*>(
                &base[(size_t)(b0 + ty*4 + q) * OUTDIM + j0 + tx*4]);
            psum[q][0] += pv.x; psum[q][1] += pv.y;
            psum[q][2] += pv.z; psum[q][3] += pv.w;
        }
    }

    #pragma unroll
    for (int q = 0; q < 4; ++q)
        #pragma unroll
        for (int p = 0; p < 4; ++p) {
            float v = acc[q][p];
            float sv = v / (1.f + __expf(-v));
            out[(size_t)(b0 + ty*4 + q) * OUTDIM + (j0 + tx*4 + p)] =
                sv + psum[q][p];
        }
}

// ---------------------------------------------------------------------------
extern "C" void kernel_launch(void* const* d_in, const int* in_sizes, int n_in,
                              void* d_out, int out_size, void* d_ws, size_t ws_size,
                              hipStream_t stream) {
    const float* x  = (const float*)d_in[0];   // [2048, 256]
    const float* bw = (const float*)d_in[1];   // [256, 256]
    const float* fc = (const float*)d_in[2];   // [2, 256, 256, 300]
    float* out = (float*)d_out;                // [2048, 256]

    const size_t per = (size_t)BATCH * OUTDIM * sizeof(float);   // 2 MB/split

    if (ws_size >= PACKED_BYTES + 32 * per) {
        // main path: pack -> DMA fourier -> combine
        uint4* pk   = (uint4*)d_ws;
        float* part = (float*)((char*)d_ws + PACKED_BYTES);
        pack_kernel<<<(int)(PACKED_U4 / 256), 256, 0, stream>>>(fc, pk);
        fourier_dma_kernel<<<dim3(16, 1, 32), 256, 0, stream>>>(x, pk, part);
        combine_kernel<<<dim3(BATCH / 64, OUTDIM / 64), 256, 0, stream>>>(
            x, bw, part, out, 32);
    } else {
        // fallback: round-2 path, auto-shrunk split count
        float* part = (float*)d_ws;
        int S = 32;
        while (S > 1 && (size_t)S * per > ws_size) S >>= 1;
        const int ips = INDIM / S;
        fourier_kernel_fb<<<dim3(BATCH / 256, OUTDIM / 128, S), 256, 0, stream>>>(
            x, fc, part, ips);
        combine_kernel<<<dim3(BATCH / 64, OUTDIM / 64), 256, 0, stream>>>(
            x, bw, part, out, S);
    }
}